// Round 1
// 149.546 us; speedup vs baseline: 1.0796x; 1.0796x over previous
//
#include <hip/hip_runtime.h>
#include <math.h>

// Problem constants
#define BB 2
#define LL 512
#define HH 768
#define EE 512
#define RR 32768
#define H2 384
#define MM 1024   // B*E entity rows

typedef __attribute__((ext_vector_type(8))) short     bf16x8;  // MFMA A/B frag (4 VGPRs)
typedef __attribute__((ext_vector_type(4))) float     f32x4;   // MFMA C/D frag
typedef __attribute__((ext_vector_type(8))) unsigned short u16x8;

__device__ __forceinline__ unsigned short f2bf(float f) {
    unsigned int u = __float_as_uint(f);
    u = (u + 0x7FFFu + ((u >> 16) & 1u)) >> 16;   // round-to-nearest-even
    return (unsigned short)u;
}

// ---------------------------------------------------------------------------
// prep:
//   blocks [0,2016)    transpose+convert weights [K][N] fp32 -> [N][K] bf16.
//                      W1 only needs its TOP half (rows 0..767) transposed —
//                      the bottom half (emb input) is folded into embc.
//   blocks [2016,3040) gather hidden[b, ent_start] -> Hbf bf16 [1024][768]
//   blocks [3040,3064) embc[l][n] = b1[n] + sum_k emb[l][k]*W1[768+k][n]
//                      (n spans cat(head cols, tail cols), 24 blocks x 64 cols,
//                       4 waves split k, LDS reduce)
// ---------------------------------------------------------------------------
__global__ __launch_bounds__(256) void prep(
    const float* __restrict__ hW1, const float* __restrict__ tW1,
    const float* __restrict__ hW2, const float* __restrict__ tW2,
    const float* __restrict__ bilW,
    unsigned short* __restrict__ W1ht, unsigned short* __restrict__ W1tt,
    unsigned short* __restrict__ W2ht, unsigned short* __restrict__ W2tt,
    unsigned short* __restrict__ bW0t, unsigned short* __restrict__ bW1t,
    const float* __restrict__ hidden, const int* __restrict__ ent_start,
    const int* __restrict__ ent_label, const float* __restrict__ emb,
    const float* __restrict__ hb1, const float* __restrict__ tb1,
    unsigned short* __restrict__ Hbf, float* __restrict__ embc)
{
    __shared__ unsigned short T[32 * 40];
    __shared__ float red[4][192];
    const int bid = blockIdx.x;
    const int t = threadIdx.x;

    if (bid >= 3040) {
        // ---- embc: per-(label, col) folded bias table
        const int eb = bid - 3040;           // 0..23
        const int tc = t & 63;
        const int kg = t >> 6;               // 0..3 k-group
        const int n = eb * 64 + tc;          // global col 0..1535
        const float* W = (n < 768) ? hW1 : tW1;
        const int cc = (n < 768) ? n : n - 768;
        float a0 = 0.f, a1 = 0.f, a2 = 0.f;
        const int kbeg = kg * 192;
        #pragma unroll 8
        for (int k = kbeg; k < kbeg + 192; ++k) {
            const float w = W[(size_t)(768 + k) * 768 + cc];
            a0 += emb[k] * w;
            a1 += emb[768 + k] * w;
            a2 += emb[1536 + k] * w;
        }
        red[kg][0 * 64 + tc] = a0;
        red[kg][1 * 64 + tc] = a1;
        red[kg][2 * 64 + tc] = a2;
        __syncthreads();
        if (kg == 0) {
            const float b = (n < 768) ? hb1[n] : tb1[n - 768];
            #pragma unroll
            for (int l = 0; l < 3; ++l) {
                embc[l * 1536 + n] = b + red[0][l * 64 + tc] + red[1][l * 64 + tc]
                                       + red[2][l * 64 + tc] + red[3][l * 64 + tc];
            }
        }
        return;
    }

    if (bid >= 2016) {
        // ---- gather hidden[b, ent_start[m]] as bf16 (768 cols)
        const int m = bid - 2016;            // 0..1023
        if (t >= 96) return;
        const int b = m >> 9;
        const int idx = ent_start[m];
        const float4* s = (const float4*)(hidden + (size_t)(b * LL + idx) * HH);
        const float4 v0 = s[2 * t];
        const float4 v1 = s[2 * t + 1];
        u16x8 o;
        o[0] = f2bf(v0.x); o[1] = f2bf(v0.y); o[2] = f2bf(v0.z); o[3] = f2bf(v0.w);
        o[4] = f2bf(v1.x); o[5] = f2bf(v1.y); o[6] = f2bf(v1.z); o[7] = f2bf(v1.w);
        *(u16x8*)(Hbf + (size_t)m * 768 + 8 * t) = o;
        return;
    }

    // ---- weight transpose (32x32 tile per block)
    const float* src; unsigned short* dst; int K, N, tile;
    if (bid < 576)       { src = hW1;            dst = W1ht; K = 768; N = 768; tile = bid; }
    else if (bid < 1152) { src = tW1;            dst = W1tt; K = 768; N = 768; tile = bid - 576; }
    else if (bid < 1440) { src = hW2;            dst = W2ht; K = 768; N = 384; tile = bid - 1152; }
    else if (bid < 1728) { src = tW2;            dst = W2tt; K = 768; N = 384; tile = bid - 1440; }
    else if (bid < 1872) { src = bilW;           dst = bW0t; K = 384; N = 384; tile = bid - 1728; }
    else                 { src = bilW + 384*384; dst = bW1t; K = 384; N = 384; tile = bid - 1872; }
    const int tn = N >> 5;
    const int n0 = (tile % tn) * 32;
    const int k0 = (tile / tn) * 32;

    const int r  = t >> 3;           // 0..31 (k within tile)
    const int c4 = (t & 7) * 4;      // 0..28 (n within tile)
    const float4 g = *(const float4*)(src + (size_t)(k0 + r) * N + n0 + c4);
    T[(c4 + 0) * 40 + r] = f2bf(g.x);
    T[(c4 + 1) * 40 + r] = f2bf(g.y);
    T[(c4 + 2) * 40 + r] = f2bf(g.z);
    T[(c4 + 3) * 40 + r] = f2bf(g.w);
    __syncthreads();
    const int n  = t >> 3;           // 0..31
    const int k4 = (t & 7) * 4;      // 0..28
    *(ushort4*)(dst + (size_t)(n0 + n) * K + k0 + k4) = *(ushort4*)&T[n * 40 + k4];
}

// ---------------------------------------------------------------------------
// bf16 MFMA GEMM. 64x64 tile, 256 threads (4 waves, 2x2), 16x16x32 MFMA.
// A: [M][lda] bf16 row-major (k-contiguous); half 1 (n0>=Nh) uses k-offset
//    aoff1 into A and B matrix Bt1.
// B: transposed [*][ldb] bf16; row index gets +((m0>>9)*bt_mrow) for
//    batch-blocked GEMMs (bt_mrow=512) so B rows come from A's batch.
// C = act(A·B + bias): written fp32 (Cf) and/or bf16 (Cb), ldc = full N.
// EB: per-(row-label, col) bias table embc[3][1536] (layer1 emb folding).
// O2: interleaved fp32 output col' = 2*(col within half) + half  (Stab).
// K-loop prefetches tile k+1's staging regs before tile k's MFMAs so the
// vmcnt(0) drain at the next barrier is covered by ds_read+MFMA work.
// LDS rows padded to 40 bf16 (80 B): staging + frag reads at bank floor.
// ---------------------------------------------------------------------------
template<bool RELU, bool BIAS, bool EB, bool WF32, bool WBF16, bool O2>
__global__ __launch_bounds__(256) void gemm_mfma(
    const unsigned short* __restrict__ A, int lda, int aoff1,
    const unsigned short* __restrict__ Bt0, const unsigned short* __restrict__ Bt1,
    int ldb, int bt_mrow, int Nh,
    const float* __restrict__ bias0, const float* __restrict__ bias1,
    const float* __restrict__ embc, const int* __restrict__ labels,
    int K, float* __restrict__ Cf, unsigned short* __restrict__ Cb, int ldc)
{
    __shared__ unsigned short As[64 * 40];
    __shared__ unsigned short Bs[64 * 40];

    const int tid = threadIdx.x;
    const int n0 = blockIdx.x * 64;
    const int m0 = blockIdx.y * 64;
    const int hf = (n0 >= Nh) ? 1 : 0;
    const unsigned short* Bt = hf ? Bt1 : Bt0;
    const int nc0 = n0 - (hf ? Nh : 0);
    const int aoff = hf ? aoff1 : 0;

    // staging: thread t covers row sr (m for A, n for B), 8 bf16 at k-offset sk
    const int sr = tid >> 2;            // 0..63
    const int sk = (tid & 3) * 8;       // 0,8,16,24

    const unsigned short* Ap = A + (size_t)(m0 + sr) * lda + aoff + sk;
    const unsigned short* Bp = Bt + (size_t)((m0 >> 9) * bt_mrow + nc0 + sr) * ldb + sk;

    const int lane = tid & 63;
    const int wave = tid >> 6;
    const int wm = (wave & 1) * 32;
    const int wn = (wave >> 1) * 32;
    const int l15 = lane & 15;
    const int quad = lane >> 4;

    f32x4 acc00 = {}, acc01 = {}, acc10 = {}, acc11 = {};

    // prologue: prefetch tile 0
    u16x8 av = *(const u16x8*)(Ap);
    u16x8 bv = *(const u16x8*)(Bp);

    for (int k0 = 0; k0 < K; k0 += 32) {
        __syncthreads();                 // previous iter's readers done
        *(u16x8*)&As[sr * 40 + sk] = av;
        *(u16x8*)&Bs[sr * 40 + sk] = bv;
        __syncthreads();
        if (k0 + 32 < K) {               // prefetch next tile before MFMAs
            av = *(const u16x8*)(Ap + k0 + 32);
            bv = *(const u16x8*)(Bp + k0 + 32);
        }
        const bf16x8 a0 = *(const bf16x8*)&As[(wm + l15) * 40 + quad * 8];
        const bf16x8 a1 = *(const bf16x8*)&As[(wm + 16 + l15) * 40 + quad * 8];
        const bf16x8 b0 = *(const bf16x8*)&Bs[(wn + l15) * 40 + quad * 8];
        const bf16x8 b1 = *(const bf16x8*)&Bs[(wn + 16 + l15) * 40 + quad * 8];
        acc00 = __builtin_amdgcn_mfma_f32_16x16x32_bf16(a0, b0, acc00, 0, 0, 0);
        acc01 = __builtin_amdgcn_mfma_f32_16x16x32_bf16(a0, b1, acc01, 0, 0, 0);
        acc10 = __builtin_amdgcn_mfma_f32_16x16x32_bf16(a1, b0, acc10, 0, 0, 0);
        acc11 = __builtin_amdgcn_mfma_f32_16x16x32_bf16(a1, b1, acc11, 0, 0, 0);
    }

    // epilogue: C/D layout col=lane&15, row=quad*4+reg
    float bias_v0 = 0.f, bias_v1 = 0.f;
    if (BIAS) {
        const float* bb = hf ? bias1 : bias0;
        bias_v0 = bb[nc0 + wn + l15];
        bias_v1 = bb[nc0 + wn + 16 + l15];
    }
    const f32x4 accs[2][2] = {{acc00, acc01}, {acc10, acc11}};
    #pragma unroll
    for (int mi = 0; mi < 2; ++mi) {
        int labr[4];
        if (EB) {
            #pragma unroll
            for (int r = 0; r < 4; ++r)
                labr[r] = labels[m0 + wm + mi * 16 + quad * 4 + r];
        }
        #pragma unroll
        for (int ni = 0; ni < 2; ++ni) {
            const int col = n0 + wn + ni * 16 + l15;
            const float bv = ni ? bias_v1 : bias_v0;
            int colw = col;
            if (O2) colw = 2 * (nc0 + wn + ni * 16 + l15) + hf;
            #pragma unroll
            for (int r = 0; r < 4; ++r) {
                const int row = m0 + wm + mi * 16 + quad * 4 + r;
                float v = accs[mi][ni][r];
                if (BIAS) v += bv;
                if (EB) v += embc[labr[r] * 1536 + col];
                if (RELU) v = fmaxf(v, 0.f);
                if (WF32) Cf[(size_t)row * ldc + colw] = v;
                if (WBF16) Cb[(size_t)row * ldc + colw] = f2bf(v);
            }
        }
    }
}

// ---------------------------------------------------------------------------
// hlin[m,o] = dot(heads[m], lin_W[0:384, o]); tlin from lin_W[384:768].
// ---------------------------------------------------------------------------
__global__ __launch_bounds__(256) void lin_proj(
    const float* __restrict__ HT, const float* __restrict__ linW,
    float* __restrict__ hlin, float* __restrict__ tlin)
{
    const int tid = threadIdx.x;
    const int lane = tid & 63;
    const int wave = tid >> 6;
    const int m = blockIdx.x * 4 + wave;
    const float* hr = HT + (size_t)m * 768;
    const float* tr = hr + 384;
    float hl0 = 0.f, hl1 = 0.f, tl0 = 0.f, tl1 = 0.f;
    #pragma unroll
    for (int t = 0; t < 6; ++t) {
        const int c = lane + 64 * t;
        const float hv = hr[c];
        const float tv = tr[c];
        const float2 wh = *(const float2*)(linW + 2 * c);
        const float2 wt = *(const float2*)(linW + 2 * (384 + c));
        hl0 += hv * wh.x; hl1 += hv * wh.y;
        tl0 += tv * wt.x; tl1 += tv * wt.y;
    }
    #pragma unroll
    for (int o = 32; o >= 1; o >>= 1) {
        hl0 += __shfl_xor(hl0, o, 64);
        hl1 += __shfl_xor(hl1, o, 64);
        tl0 += __shfl_xor(tl0, o, 64);
        tl1 += __shfl_xor(tl1, o, 64);
    }
    if (lane == 0) {
        hlin[2 * m]     = hl0;
        hlin[2 * m + 1] = hl1;
        tlin[2 * m]     = tl0;
        tlin[2 * m + 1] = tl1;
    }
}

// ---------------------------------------------------------------------------
// Per-relation gather from the E×E score table + CE partials.
// One thread per relation. Stab interleaved: Stab[mh][2*t + o].
// ---------------------------------------------------------------------------
__global__ __launch_bounds__(256) void rel_gather(
    const float* __restrict__ Stab,
    const float* __restrict__ hlin, const float* __restrict__ tlin,
    const float* __restrict__ lin_b,
    const int* __restrict__ rel_head, const int* __restrict__ rel_tail,
    const int* __restrict__ rel_label,
    float* __restrict__ out, float* __restrict__ bsum)
{
    const int tid = threadIdx.x;
    const int i = blockIdx.x * 256 + tid;       // relation 0..65535
    const int b = i >> 15;
    const int h = rel_head[i];
    const int t = rel_tail[i];
    const int lab = rel_label[i];
    const int mh = (b << 9) + h;
    const int mt = (b << 9) + t;

    const float2 hl = ((const float2*)hlin)[mh];
    const float2 tl = ((const float2*)tlin)[mt];
    const float2 zz = *(const float2*)(Stab + (size_t)mh * 1024 + 2 * t);
    const float z0 = zz.x + hl.x + tl.x + lin_b[0];
    const float z1 = zz.y + hl.y + tl.y + lin_b[1];
    out[1 + 2 * (size_t)i]     = z0;
    out[2 + 2 * (size_t)i]     = z1;

    const float mx = fmaxf(z0, z1);
    const float mn = fminf(z0, z1);
    const float lse = mx + log1pf(expf(mn - mx));
    float ce = lse - (lab ? z1 : z0);

    // block reduce (4 waves)
    #pragma unroll
    for (int o = 32; o >= 1; o >>= 1) ce += __shfl_xor(ce, o, 64);
    __shared__ float wsum[4];
    if ((tid & 63) == 0) wsum[tid >> 6] = ce;
    __syncthreads();
    if (tid == 0) bsum[blockIdx.x] = wsum[0] + wsum[1] + wsum[2] + wsum[3];
}

__global__ __launch_bounds__(256) void finalize(
    const float* __restrict__ bsum, float* __restrict__ out)
{
    const int tid = threadIdx.x;
    float v = bsum[tid];
    #pragma unroll
    for (int o = 32; o >= 1; o >>= 1) v += __shfl_xor(v, o, 64);
    __shared__ float s[4];
    if ((tid & 63) == 0) s[tid >> 6] = v;
    __syncthreads();
    if (tid == 0) {
        out[0] = (s[0] + s[1] + s[2] + s[3]) * (1.0f / (float)RR);
    }
}

// ---------------------------------------------------------------------------
extern "C" void kernel_launch(void* const* d_in, const int* in_sizes, int n_in,
                              void* d_out, int out_size, void* d_ws, size_t ws_size,
                              hipStream_t stream) {
    const float* hidden    = (const float*)d_in[0];
    const int*   ent_start = (const int*)d_in[1];
    const int*   ent_label = (const int*)d_in[2];
    const int*   rel_head  = (const int*)d_in[3];
    const int*   rel_tail  = (const int*)d_in[4];
    const int*   rel_label = (const int*)d_in[5];
    const float* emb       = (const float*)d_in[6];
    const float* head_W1   = (const float*)d_in[7];
    const float* head_b1   = (const float*)d_in[8];
    const float* head_W2   = (const float*)d_in[9];
    const float* head_b2   = (const float*)d_in[10];
    const float* tail_W1   = (const float*)d_in[11];
    const float* tail_b1   = (const float*)d_in[12];
    const float* tail_W2   = (const float*)d_in[13];
    const float* tail_b2   = (const float*)d_in[14];
    const float* bil_W     = (const float*)d_in[15];
    const float* lin_W     = (const float*)d_in[16];
    const float* lin_b     = (const float*)d_in[17];
    float* out = (float*)d_out;

    // Workspace carve-up (256B-aligned chunks)
    char* w = (char*)d_ws;
    auto carve = [&](size_t bytes) {
        char* p = w; w += (bytes + 255) & ~(size_t)255; return p;
    };
    unsigned short* Hbf  = (unsigned short*)carve((size_t)MM * 768 * 2);
    unsigned short* Y1bf = (unsigned short*)carve((size_t)MM * 1536 * 2);
    unsigned short* HTbf = (unsigned short*)carve((size_t)MM * 768 * 2);
    float*          HT   = (float*)carve((size_t)MM * 768 * 4);
    unsigned short* hWbf = (unsigned short*)carve((size_t)MM * 768 * 2);
    float*          Stab = (float*)carve((size_t)MM * 1024 * 4);
    unsigned short* W1ht = (unsigned short*)carve((size_t)768 * 768 * 2);
    unsigned short* W1tt = (unsigned short*)carve((size_t)768 * 768 * 2);
    unsigned short* W2ht = (unsigned short*)carve((size_t)384 * 768 * 2);
    unsigned short* W2tt = (unsigned short*)carve((size_t)384 * 768 * 2);
    unsigned short* bW0t = (unsigned short*)carve((size_t)384 * 384 * 2);
    unsigned short* bW1t = (unsigned short*)carve((size_t)384 * 384 * 2);
    float*          embc = (float*)carve((size_t)3 * 1536 * 4);
    float*          hlin = (float*)carve(2048 * 4);
    float*          tlin = (float*)carve(2048 * 4);
    float*          bsum = (float*)carve(256 * 4);

    // 1) weight transpose->bf16 + hidden gather->bf16 + embc fold (one launch)
    prep<<<3064, 256, 0, stream>>>(
        head_W1, tail_W1, head_W2, tail_W2, bil_W,
        W1ht, W1tt, W2ht, W2tt, bW0t, bW1t,
        hidden, ent_start, ent_label, emb, head_b1, tail_b1, Hbf, embc);

    // 2) layer1: Y1 = relu(Hbf @ [W1h'|W1t'] + embc[lab]), N=1536 (Nh=768), K=768
    gemm_mfma<true, false, true, false, true, false><<<dim3(24, 16), 256, 0, stream>>>(
        Hbf, 768, 0, W1ht, W1tt, 768, 0, 768, nullptr, nullptr, embc, ent_label,
        768, nullptr, Y1bf, 1536);

    // 3) layer2: HT = relu(Y1 @ [W2h|W2t] + b2), N=768 (Nh=384), K=768,
    //    tail half reads Y1 cols 768.. ; outputs fp32 + bf16
    gemm_mfma<true, true, false, true, true, false><<<dim3(12, 16), 256, 0, stream>>>(
        Y1bf, 1536, 768, W2ht, W2tt, 768, 0, 384, head_b2, tail_b2, nullptr, nullptr,
        768, HT, HTbf, 768);

    // 4) bilinear left product: hWbf = heads @ bil_W[o], N=768 (Nh=384), K=384
    gemm_mfma<false, false, false, false, true, false><<<dim3(12, 16), 256, 0, stream>>>(
        HTbf, 768, 0, bW0t, bW1t, 384, 0, 384, nullptr, nullptr, nullptr, nullptr,
        384, nullptr, hWbf, 768);

    // 5) score table (o-interleaved): Stab[mh][2*t+o] = hWbf[mh, o*384:..] . tails[b,t,:]
    gemm_mfma<false, false, false, true, false, true><<<dim3(16, 16), 256, 0, stream>>>(
        hWbf, 768, 384, HTbf + 384, HTbf + 384, 768, 512, 512,
        nullptr, nullptr, nullptr, nullptr, 384, Stab, nullptr, 1024);

    // 6) scalar linear projections
    lin_proj<<<256, 256, 0, stream>>>(HT, lin_W, hlin, tlin);

    // 7) per-relation gather + CE partials
    rel_gather<<<256, 256, 0, stream>>>(Stab, hlin, tlin, lin_b,
                                        rel_head, rel_tail, rel_label, out, bsum);

    // 8) loss reduction
    finalize<<<1, 256, 0, stream>>>(bsum, out);
}

// Round 2
// 142.458 us; speedup vs baseline: 1.1334x; 1.0498x over previous
//
#include <hip/hip_runtime.h>
#include <math.h>

// Problem constants
#define BB 2
#define LL 512
#define HH 768
#define EE 512
#define RR 32768
#define H2 384
#define MM 1024   // B*E entity rows

typedef __attribute__((ext_vector_type(8))) short     bf16x8;  // MFMA A/B frag (4 VGPRs)
typedef __attribute__((ext_vector_type(4))) float     f32x4;   // MFMA C/D frag
typedef __attribute__((ext_vector_type(8))) unsigned short u16x8;

__device__ __forceinline__ unsigned short f2bf(float f) {
    unsigned int u = __float_as_uint(f);
    u = (u + 0x7FFFu + ((u >> 16) & 1u)) >> 16;   // round-to-nearest-even
    return (unsigned short)u;
}

// ---------------------------------------------------------------------------
// prep:
//   blocks [0,2016)    transpose+convert weights [K][N] fp32 -> [N][K] bf16.
//   blocks [2016,3040) gather hidden[b, ent_start] -> Hbf bf16 [1024][768]
//   blocks [3040,3064) embc[l][n] = b1[n] + sum_k emb[l][k]*W1[768+k][n]
//   block  3064        zero hlin/tlin accumulators + out[0]
// ---------------------------------------------------------------------------
__global__ __launch_bounds__(256) void prep(
    const float* __restrict__ hW1, const float* __restrict__ tW1,
    const float* __restrict__ hW2, const float* __restrict__ tW2,
    const float* __restrict__ bilW,
    unsigned short* __restrict__ W1ht, unsigned short* __restrict__ W1tt,
    unsigned short* __restrict__ W2ht, unsigned short* __restrict__ W2tt,
    unsigned short* __restrict__ bW0t, unsigned short* __restrict__ bW1t,
    const float* __restrict__ hidden, const int* __restrict__ ent_start,
    const int* __restrict__ ent_label, const float* __restrict__ emb,
    const float* __restrict__ hb1, const float* __restrict__ tb1,
    unsigned short* __restrict__ Hbf, float* __restrict__ embc,
    float* __restrict__ hlin, float* __restrict__ tlin, float* __restrict__ out)
{
    __shared__ unsigned short T[32 * 40];
    __shared__ float red[4][192];
    const int bid = blockIdx.x;
    const int t = threadIdx.x;

    if (bid == 3064) {
        // ---- zero the atomic accumulators (hlin/tlin: 2048 floats each)
        const float4 z = {0.f, 0.f, 0.f, 0.f};
        ((float4*)hlin)[t] = z; ((float4*)hlin)[256 + t] = z;
        ((float4*)tlin)[t] = z; ((float4*)tlin)[256 + t] = z;
        if (t == 0) out[0] = 0.f;
        return;
    }

    if (bid >= 3040) {
        // ---- embc: per-(label, col) folded bias table
        const int eb = bid - 3040;           // 0..23
        const int tc = t & 63;
        const int kg = t >> 6;               // 0..3 k-group
        const int n = eb * 64 + tc;          // global col 0..1535
        const float* W = (n < 768) ? hW1 : tW1;
        const int cc = (n < 768) ? n : n - 768;
        float a0 = 0.f, a1 = 0.f, a2 = 0.f;
        const int kbeg = kg * 192;
        #pragma unroll 8
        for (int k = kbeg; k < kbeg + 192; ++k) {
            const float w = W[(size_t)(768 + k) * 768 + cc];
            a0 += emb[k] * w;
            a1 += emb[768 + k] * w;
            a2 += emb[1536 + k] * w;
        }
        red[kg][0 * 64 + tc] = a0;
        red[kg][1 * 64 + tc] = a1;
        red[kg][2 * 64 + tc] = a2;
        __syncthreads();
        if (kg == 0) {
            const float b = (n < 768) ? hb1[n] : tb1[n - 768];
            #pragma unroll
            for (int l = 0; l < 3; ++l) {
                embc[l * 1536 + n] = b + red[0][l * 64 + tc] + red[1][l * 64 + tc]
                                       + red[2][l * 64 + tc] + red[3][l * 64 + tc];
            }
        }
        return;
    }

    if (bid >= 2016) {
        // ---- gather hidden[b, ent_start[m]] as bf16 (768 cols)
        const int m = bid - 2016;            // 0..1023
        if (t >= 96) return;
        const int b = m >> 9;
        const int idx = ent_start[m];
        const float4* s = (const float4*)(hidden + (size_t)(b * LL + idx) * HH);
        const float4 v0 = s[2 * t];
        const float4 v1 = s[2 * t + 1];
        u16x8 o;
        o[0] = f2bf(v0.x); o[1] = f2bf(v0.y); o[2] = f2bf(v0.z); o[3] = f2bf(v0.w);
        o[4] = f2bf(v1.x); o[5] = f2bf(v1.y); o[6] = f2bf(v1.z); o[7] = f2bf(v1.w);
        *(u16x8*)(Hbf + (size_t)m * 768 + 8 * t) = o;
        return;
    }

    // ---- weight transpose (32x32 tile per block)
    const float* src; unsigned short* dst; int K, N, tile;
    if (bid < 576)       { src = hW1;            dst = W1ht; K = 768; N = 768; tile = bid; }
    else if (bid < 1152) { src = tW1;            dst = W1tt; K = 768; N = 768; tile = bid - 576; }
    else if (bid < 1440) { src = hW2;            dst = W2ht; K = 768; N = 384; tile = bid - 1152; }
    else if (bid < 1728) { src = tW2;            dst = W2tt; K = 768; N = 384; tile = bid - 1440; }
    else if (bid < 1872) { src = bilW;           dst = bW0t; K = 384; N = 384; tile = bid - 1728; }
    else                 { src = bilW + 384*384; dst = bW1t; K = 384; N = 384; tile = bid - 1872; }
    const int tn = N >> 5;
    const int n0 = (tile % tn) * 32;
    const int k0 = (tile / tn) * 32;

    const int r  = t >> 3;           // 0..31 (k within tile)
    const int c4 = (t & 7) * 4;      // 0..28 (n within tile)
    const float4 g = *(const float4*)(src + (size_t)(k0 + r) * N + n0 + c4);
    T[(c4 + 0) * 40 + r] = f2bf(g.x);
    T[(c4 + 1) * 40 + r] = f2bf(g.y);
    T[(c4 + 2) * 40 + r] = f2bf(g.z);
    T[(c4 + 3) * 40 + r] = f2bf(g.w);
    __syncthreads();
    const int n  = t >> 3;           // 0..31
    const int k4 = (t & 7) * 4;      // 0..28
    *(ushort4*)(dst + (size_t)(n0 + n) * K + k0 + k4) = *(ushort4*)&T[n * 40 + k4];
}

// ---------------------------------------------------------------------------
// bf16 MFMA GEMM. 64x64 tile, 256 threads (4 waves, 2x2), 16x16x32 MFMA.
// K_STEP=64, double-buffered LDS, ONE raw s_barrier per K-step (no vmcnt
// drain: prefetch loads for tile k+1 stay in flight across the barrier; the
// compiler's vmcnt wait lands at the ds_write, after the MFMA cluster).
// A: [M][lda] bf16 row-major; half 1 (n0>=Nh) uses k-offset aoff1 + Bt1.
// B: transposed [*][ldb] bf16; +((m0>>9)*bt_mrow) row offset for the
//    batch-blocked score GEMM.
// EB:  per-(row-label, col) bias table embc[3][1536] (layer1 emb folding).
// O2:  interleaved fp32 output col' = 2*(col within half) + half  (Stab).
// LIN: epilogue also reduces v·linW[col] per row (quad-wide shfl reduce)
//      and atomicAdds into hlin/tlin (fused lin_proj).
// ---------------------------------------------------------------------------
template<bool RELU, bool BIAS, bool EB, bool WF32, bool WBF16, bool O2, bool LIN>
__global__ __launch_bounds__(256) void gemm_mfma(
    const unsigned short* __restrict__ A, int lda, int aoff1,
    const unsigned short* __restrict__ Bt0, const unsigned short* __restrict__ Bt1,
    int ldb, int bt_mrow, int Nh,
    const float* __restrict__ bias0, const float* __restrict__ bias1,
    const float* __restrict__ embc, const int* __restrict__ labels,
    const float* __restrict__ linW, float* __restrict__ hlin, float* __restrict__ tlin,
    int K, float* __restrict__ Cf, unsigned short* __restrict__ Cb, int ldc)
{
    __shared__ unsigned short As[2][64 * 72];
    __shared__ unsigned short Bs[2][64 * 72];

    const int tid = threadIdx.x;
    const int n0 = blockIdx.x * 64;
    const int m0 = blockIdx.y * 64;
    const int hf = (n0 >= Nh) ? 1 : 0;
    const unsigned short* Bt = hf ? Bt1 : Bt0;
    const int nc0 = n0 - (hf ? Nh : 0);
    const int aoff = hf ? aoff1 : 0;

    // staging: thread t covers row sr, 16 bf16 at k-offset sk (2 x u16x8)
    const int sr = tid >> 2;            // 0..63
    const int sk = (tid & 3) * 16;      // 0,16,32,48

    const unsigned short* Ap = A + (size_t)(m0 + sr) * lda + aoff + sk;
    const unsigned short* Bp = Bt + (size_t)((m0 >> 9) * bt_mrow + nc0 + sr) * ldb + sk;

    const int lane = tid & 63;
    const int wave = tid >> 6;
    const int wm = (wave & 1) * 32;
    const int wn = (wave >> 1) * 32;
    const int l15 = lane & 15;
    const int quad = lane >> 4;

    f32x4 acc00 = {}, acc01 = {}, acc10 = {}, acc11 = {};

    // prologue: tile 0 -> regs -> LDS buf0
    u16x8 a0v = *(const u16x8*)(Ap);
    u16x8 a1v = *(const u16x8*)(Ap + 8);
    u16x8 b0v = *(const u16x8*)(Bp);
    u16x8 b1v = *(const u16x8*)(Bp + 8);
    const int swo = sr * 72 + sk;
    *(u16x8*)&As[0][swo] = a0v; *(u16x8*)&As[0][swo + 8] = a1v;
    *(u16x8*)&Bs[0][swo] = b0v; *(u16x8*)&Bs[0][swo + 8] = b1v;

    const int NT = K >> 6;
    const int aro = quad * 8;
    int cur = 0;
    for (int it = 0; it < NT; ++it) {
        if (it + 1 < NT) {              // issue next tile's loads (stay in flight)
            const int ko = (it + 1) * 64;
            a0v = *(const u16x8*)(Ap + ko); a1v = *(const u16x8*)(Ap + ko + 8);
            b0v = *(const u16x8*)(Bp + ko); b1v = *(const u16x8*)(Bp + ko + 8);
        }
        asm volatile("s_waitcnt lgkmcnt(0)" ::: "memory");  // my ds ops done
        __builtin_amdgcn_s_barrier();                        // no vmcnt drain
        __builtin_amdgcn_sched_barrier(0);
        const unsigned short* Ac = As[cur];
        const unsigned short* Bc = Bs[cur];
        const bf16x8 fa0 = *(const bf16x8*)&Ac[(wm + l15) * 72 + aro];
        const bf16x8 fa1 = *(const bf16x8*)&Ac[(wm + 16 + l15) * 72 + aro];
        const bf16x8 fb0 = *(const bf16x8*)&Bc[(wn + l15) * 72 + aro];
        const bf16x8 fb1 = *(const bf16x8*)&Bc[(wn + 16 + l15) * 72 + aro];
        const bf16x8 ga0 = *(const bf16x8*)&Ac[(wm + l15) * 72 + aro + 32];
        const bf16x8 ga1 = *(const bf16x8*)&Ac[(wm + 16 + l15) * 72 + aro + 32];
        const bf16x8 gb0 = *(const bf16x8*)&Bc[(wn + l15) * 72 + aro + 32];
        const bf16x8 gb1 = *(const bf16x8*)&Bc[(wn + 16 + l15) * 72 + aro + 32];
        acc00 = __builtin_amdgcn_mfma_f32_16x16x32_bf16(fa0, fb0, acc00, 0, 0, 0);
        acc01 = __builtin_amdgcn_mfma_f32_16x16x32_bf16(fa0, fb1, acc01, 0, 0, 0);
        acc10 = __builtin_amdgcn_mfma_f32_16x16x32_bf16(fa1, fb0, acc10, 0, 0, 0);
        acc11 = __builtin_amdgcn_mfma_f32_16x16x32_bf16(fa1, fb1, acc11, 0, 0, 0);
        acc00 = __builtin_amdgcn_mfma_f32_16x16x32_bf16(ga0, gb0, acc00, 0, 0, 0);
        acc01 = __builtin_amdgcn_mfma_f32_16x16x32_bf16(ga0, gb1, acc01, 0, 0, 0);
        acc10 = __builtin_amdgcn_mfma_f32_16x16x32_bf16(ga1, gb0, acc10, 0, 0, 0);
        acc11 = __builtin_amdgcn_mfma_f32_16x16x32_bf16(ga1, gb1, acc11, 0, 0, 0);
        if (it + 1 < NT) {              // write next tile into alternate buffer
            unsigned short* Aw = &As[cur ^ 1][0];
            unsigned short* Bw = &Bs[cur ^ 1][0];
            *(u16x8*)&Aw[swo] = a0v; *(u16x8*)&Aw[swo + 8] = a1v;
            *(u16x8*)&Bw[swo] = b0v; *(u16x8*)&Bw[swo + 8] = b1v;
        }
        cur ^= 1;
    }

    // epilogue: C/D layout col=lane&15, row=quad*4+reg
    float bias_v0 = 0.f, bias_v1 = 0.f;
    if (BIAS) {
        const float* bb = hf ? bias1 : bias0;
        bias_v0 = bb[nc0 + wn + l15];
        bias_v1 = bb[nc0 + wn + 16 + l15];
    }
    const int col0 = n0 + wn + l15;
    const int col1 = col0 + 16;
    int colw0 = col0, colw1 = col1;
    if (O2) {
        colw0 = 2 * (nc0 + wn + l15) + hf;
        colw1 = 2 * (nc0 + wn + 16 + l15) + hf;
    }
    float2 lw0 = {0.f, 0.f}, lw1 = {0.f, 0.f};
    float* lout = nullptr;
    if (LIN) {
        lw0 = ((const float2*)linW)[col0];   // linW row == full output col
        lw1 = ((const float2*)linW)[col1];
        lout = hf ? tlin : hlin;
    }
    const f32x4 accs[2][2] = {{acc00, acc01}, {acc10, acc11}};
    #pragma unroll
    for (int mi = 0; mi < 2; ++mi) {
        #pragma unroll
        for (int r = 0; r < 4; ++r) {
            const int row = m0 + wm + mi * 16 + quad * 4 + r;
            float v0 = accs[mi][0][r];
            float v1 = accs[mi][1][r];
            if (BIAS) { v0 += bias_v0; v1 += bias_v1; }
            if (EB) {
                const int lab = labels[row];
                v0 += embc[lab * 1536 + col0];
                v1 += embc[lab * 1536 + col1];
            }
            if (RELU) { v0 = fmaxf(v0, 0.f); v1 = fmaxf(v1, 0.f); }
            if (WF32) {
                Cf[(size_t)row * ldc + colw0] = v0;
                Cf[(size_t)row * ldc + colw1] = v1;
            }
            if (WBF16) {
                Cb[(size_t)row * ldc + colw0] = f2bf(v0);
                Cb[(size_t)row * ldc + colw1] = f2bf(v1);
            }
            if (LIN) {
                float s0 = v0 * lw0.x + v1 * lw1.x;
                float s1 = v0 * lw0.y + v1 * lw1.y;
                #pragma unroll
                for (int o = 8; o >= 1; o >>= 1) {
                    s0 += __shfl_xor(s0, o, 64);
                    s1 += __shfl_xor(s1, o, 64);
                }
                if (l15 == 0) {
                    atomicAdd(&lout[2 * row],     s0);
                    atomicAdd(&lout[2 * row + 1], s1);
                }
            }
        }
    }
}

// ---------------------------------------------------------------------------
// Per-relation gather from the E×E score table + CE reduction (fused loss).
// One thread per relation. Stab interleaved: Stab[mh][2*t + o].
// ---------------------------------------------------------------------------
__global__ __launch_bounds__(256) void rel_gather(
    const float* __restrict__ Stab,
    const float* __restrict__ hlin, const float* __restrict__ tlin,
    const float* __restrict__ lin_b,
    const int* __restrict__ rel_head, const int* __restrict__ rel_tail,
    const int* __restrict__ rel_label,
    float* __restrict__ out)
{
    const int tid = threadIdx.x;
    const int i = blockIdx.x * 256 + tid;       // relation 0..65535
    const int b = i >> 15;
    const int h = rel_head[i];
    const int t = rel_tail[i];
    const int lab = rel_label[i];
    const int mh = (b << 9) + h;
    const int mt = (b << 9) + t;

    const float2 hl = ((const float2*)hlin)[mh];
    const float2 tl = ((const float2*)tlin)[mt];
    const float2 zz = *(const float2*)(Stab + (size_t)mh * 1024 + 2 * t);
    const float z0 = zz.x + hl.x + tl.x + lin_b[0];
    const float z1 = zz.y + hl.y + tl.y + lin_b[1];
    out[1 + 2 * (size_t)i]     = z0;
    out[2 + 2 * (size_t)i]     = z1;

    const float mx = fmaxf(z0, z1);
    const float mn = fminf(z0, z1);
    const float lse = mx + log1pf(expf(mn - mx));
    float ce = lse - (lab ? z1 : z0);

    // block reduce (4 waves) then one atomic into out[0]
    #pragma unroll
    for (int o = 32; o >= 1; o >>= 1) ce += __shfl_xor(ce, o, 64);
    __shared__ float wsum[4];
    if ((tid & 63) == 0) wsum[tid >> 6] = ce;
    __syncthreads();
    if (tid == 0) {
        const float bs = wsum[0] + wsum[1] + wsum[2] + wsum[3];
        atomicAdd(out, bs * (1.0f / (float)RR));
    }
}

// ---------------------------------------------------------------------------
extern "C" void kernel_launch(void* const* d_in, const int* in_sizes, int n_in,
                              void* d_out, int out_size, void* d_ws, size_t ws_size,
                              hipStream_t stream) {
    const float* hidden    = (const float*)d_in[0];
    const int*   ent_start = (const int*)d_in[1];
    const int*   ent_label = (const int*)d_in[2];
    const int*   rel_head  = (const int*)d_in[3];
    const int*   rel_tail  = (const int*)d_in[4];
    const int*   rel_label = (const int*)d_in[5];
    const float* emb       = (const float*)d_in[6];
    const float* head_W1   = (const float*)d_in[7];
    const float* head_b1   = (const float*)d_in[8];
    const float* head_W2   = (const float*)d_in[9];
    const float* head_b2   = (const float*)d_in[10];
    const float* tail_W1   = (const float*)d_in[11];
    const float* tail_b1   = (const float*)d_in[12];
    const float* tail_W2   = (const float*)d_in[13];
    const float* tail_b2   = (const float*)d_in[14];
    const float* bil_W     = (const float*)d_in[15];
    const float* lin_W     = (const float*)d_in[16];
    const float* lin_b     = (const float*)d_in[17];
    float* out = (float*)d_out;

    // Workspace carve-up (256B-aligned chunks)
    char* w = (char*)d_ws;
    auto carve = [&](size_t bytes) {
        char* p = w; w += (bytes + 255) & ~(size_t)255; return p;
    };
    unsigned short* Hbf  = (unsigned short*)carve((size_t)MM * 768 * 2);
    unsigned short* Y1bf = (unsigned short*)carve((size_t)MM * 1536 * 2);
    unsigned short* HTbf = (unsigned short*)carve((size_t)MM * 768 * 2);
    unsigned short* hWbf = (unsigned short*)carve((size_t)MM * 768 * 2);
    float*          Stab = (float*)carve((size_t)MM * 1024 * 4);
    unsigned short* W1ht = (unsigned short*)carve((size_t)768 * 768 * 2);
    unsigned short* W1tt = (unsigned short*)carve((size_t)768 * 768 * 2);
    unsigned short* W2ht = (unsigned short*)carve((size_t)384 * 768 * 2);
    unsigned short* W2tt = (unsigned short*)carve((size_t)384 * 768 * 2);
    unsigned short* bW0t = (unsigned short*)carve((size_t)384 * 384 * 2);
    unsigned short* bW1t = (unsigned short*)carve((size_t)384 * 384 * 2);
    float*          embc = (float*)carve((size_t)3 * 1536 * 4);
    float*          hlin = (float*)carve(2048 * 4);
    float*          tlin = (float*)carve(2048 * 4);

    // 1) weight transpose->bf16 + hidden gather->bf16 + embc fold + zeroing
    prep<<<3065, 256, 0, stream>>>(
        head_W1, tail_W1, head_W2, tail_W2, bil_W,
        W1ht, W1tt, W2ht, W2tt, bW0t, bW1t,
        hidden, ent_start, ent_label, emb, head_b1, tail_b1, Hbf, embc,
        hlin, tlin, out);

    // 2) layer1: Y1 = relu(Hbf @ [W1h'|W1t'] + embc[lab]), N=1536 (Nh=768), K=768
    gemm_mfma<true, false, true, false, true, false, false>
        <<<dim3(24, 16), 256, 0, stream>>>(
        Hbf, 768, 0, W1ht, W1tt, 768, 0, 768, nullptr, nullptr, embc, ent_label,
        nullptr, nullptr, nullptr, 768, nullptr, Y1bf, 1536);

    // 3) layer2: HTbf = relu(Y1 @ [W2h|W2t] + b2), N=768 (Nh=384), K=768,
    //    tail half reads Y1 cols 768..; epilogue fuses lin_proj via atomics
    gemm_mfma<true, true, false, false, true, false, true>
        <<<dim3(12, 16), 256, 0, stream>>>(
        Y1bf, 1536, 768, W2ht, W2tt, 768, 0, 384, head_b2, tail_b2, nullptr, nullptr,
        lin_W, hlin, tlin, 768, nullptr, HTbf, 768);

    // 4) bilinear left product: hWbf = heads @ bil_W[o], N=768 (Nh=384), K=384
    gemm_mfma<false, false, false, false, true, false, false>
        <<<dim3(12, 16), 256, 0, stream>>>(
        HTbf, 768, 0, bW0t, bW1t, 384, 0, 384, nullptr, nullptr, nullptr, nullptr,
        nullptr, nullptr, nullptr, 384, nullptr, hWbf, 768);

    // 5) score table (o-interleaved): Stab[mh][2*t+o] = hWbf[mh, o*384:..] . tails[b,t,:]
    gemm_mfma<false, false, false, true, false, true, false>
        <<<dim3(16, 16), 256, 0, stream>>>(
        hWbf, 768, 384, HTbf + 384, HTbf + 384, 768, 512, 512,
        nullptr, nullptr, nullptr, nullptr,
        nullptr, nullptr, nullptr, 384, Stab, nullptr, 1024);

    // 6) per-relation gather + CE + fused loss reduction
    rel_gather<<<256, 256, 0, stream>>>(Stab, hlin, tlin, lin_b,
                                        rel_head, rel_tail, rel_label, out);
}